// Round 4
// baseline (239.507 us; speedup 1.0000x reference)
//
#include <hip/hip_runtime.h>

#define BB 8192
#define TT 2048
#define NC 32
#define CL 64    // TT/NC
#define WUB 3    // warmup blocks of 16 steps (48 total); contraction ~0.5/step

__device__ __forceinline__ float sig2(float z) {
    return __builtin_amdgcn_rcpf(1.f + __builtin_amdgcn_exp2f(z));
}
// force a wave-uniform value into an SGPR (weights), so FMAs use the 1-SGPR slot
__device__ __forceinline__ float sgpr(float v) {
    return __builtin_bit_cast(float, __builtin_amdgcn_readfirstlane(__builtin_bit_cast(int, v)));
}
__device__ __forceinline__ void ld16(float* d, const float* p) {
    *(float4*)(d)      = *(const float4*)(p);
    *(float4*)(d + 4)  = *(const float4*)(p + 4);
    *(float4*)(d + 8)  = *(const float4*)(p + 8);
    *(float4*)(d + 12) = *(const float4*)(p + 12);
}
__device__ __forceinline__ void st16(float* p, const float* d) {
    *(float4*)(p)      = *(const float4*)(d);
    *(float4*)(p + 4)  = *(const float4*)(d + 4);
    *(float4*)(p + 8)  = *(const float4*)(d + 8);
    *(float4*)(p + 12) = *(const float4*)(d + 12);
}

#define LOAD_WHH()                                                                  \
    const float wh00=sgpr(Whh[0]*NL2E),  wh01=sgpr(Whh[1]*NL2E),                    \
                wh02=sgpr(Whh[2]*NL2E),  wh03=sgpr(Whh[3]*NL2E),                    \
                wh10=sgpr(Whh[4]*NL2E),  wh11=sgpr(Whh[5]*NL2E),                    \
                wh12=sgpr(Whh[6]*NL2E),  wh13=sgpr(Whh[7]*NL2E),                    \
                wh20=sgpr(Whh[8]*NL2E),  wh21=sgpr(Whh[9]*NL2E),                    \
                wh22=sgpr(Whh[10]*NL2E), wh23=sgpr(Whh[11]*NL2E),                   \
                wh30=sgpr(Whh[12]*NL2E), wh31=sgpr(Whh[13]*NL2E),                   \
                wh32=sgpr(Whh[14]*NL2E), wh33=sgpr(Whh[15]*NL2E);                   \
    const float wx0=sgpr(Wxh[0]*NL2E), wx1=sgpr(Wxh[1]*NL2E),                       \
                wx2=sgpr(Wxh[2]*NL2E), wx3=sgpr(Wxh[3]*NL2E);                       \
    const float bh0=sgpr(bh[0]*NL2E), bh1=sgpr(bh[1]*NL2E),                         \
                bh2=sgpr(bh[2]*NL2E), bh3=sgpr(bh[3]*NL2E);

#define HSTEP(xs)                                                                   \
    {                                                                               \
        float z0 = fmaf(h3,wh30,fmaf(h2,wh20,fmaf(h1,wh10,fmaf(h0,wh00,fmaf(xs,wx0,bh0))))); \
        float z1 = fmaf(h3,wh31,fmaf(h2,wh21,fmaf(h1,wh11,fmaf(h0,wh01,fmaf(xs,wx1,bh1))))); \
        float z2 = fmaf(h3,wh32,fmaf(h2,wh22,fmaf(h1,wh12,fmaf(h0,wh02,fmaf(xs,wx2,bh2))))); \
        float z3 = fmaf(h3,wh33,fmaf(h2,wh23,fmaf(h1,wh13,fmaf(h0,wh03,fmaf(xs,wx3,bh3))))); \
        h0 = sig2(z0); h1 = sig2(z1); h2 = sig2(z2); h3 = sig2(z3);                 \
    }

// ---------------- sweep 1: h warmup + per-chunk affine latent maps ----------------
__global__ __launch_bounds__(256, 4) void bkt_sweep1(
    const float* __restrict__ x, const float* __restrict__ Wxh,
    const float* __restrict__ Whh, const float* __restrict__ bh,
    const float* __restrict__ Wy, const float* __restrict__ by,
    float* __restrict__ AB, float* __restrict__ hstart)
{
    const int tid = blockIdx.x * 256 + threadIdx.x;   // BB*NC threads
    const int b = tid & (BB - 1);
    const int c = tid >> 13;
    const float NL2E = -1.44269504088896340736f;

    LOAD_WHH();
    const float wl0=sgpr(Wy[0]*NL2E),  wl1=sgpr(Wy[4]*NL2E),
                wl2=sgpr(Wy[8]*NL2E),  wl3=sgpr(Wy[12]*NL2E);
    const float wf0=sgpr(Wy[1]*NL2E),  wf1=sgpr(Wy[5]*NL2E),
                wf2=sgpr(Wy[9]*NL2E),  wf3=sgpr(Wy[13]*NL2E);
    const float byl=sgpr(by[0]*NL2E), byf=sgpr(by[1]*NL2E);

    const float* xr = x + (size_t)b * TT;
    float h0=0.f, h1=0.f, h2=0.f, h3=0.f;
    float xb[16];
    int t0 = c * CL;

    if (c) {                                           // uniform per wave
        t0 -= 16 * WUB;
        for (int blk = 0; blk < WUB; ++blk, t0 += 16) {
            ld16(xb, xr + t0);
            HSTEP(xb[0])  HSTEP(xb[1])  HSTEP(xb[2])  HSTEP(xb[3])
            HSTEP(xb[4])  HSTEP(xb[5])  HSTEP(xb[6])  HSTEP(xb[7])
            HSTEP(xb[8])  HSTEP(xb[9])  HSTEP(xb[10]) HSTEP(xb[11])
            HSTEP(xb[12]) HSTEP(xb[13]) HSTEP(xb[14]) HSTEP(xb[15])
        }
    }

    float A = 1.f, Bc = 0.f;
    for (int blk = 0; blk < CL / 16; ++blk, t0 += 16) {
        ld16(xb, xr + t0);
#define S1(s)                                                                       \
        {                                                                           \
            float zl = fmaf(h3,wl3,fmaf(h2,wl2,fmaf(h1,wl1,fmaf(h0,wl0,byl))));     \
            float zf = fmaf(h3,wf3,fmaf(h2,wf2,fmaf(h1,wf1,fmaf(h0,wf0,byf))));     \
            float pl = sig2(zl), pf = sig2(zf);                                     \
            float a = (1.f - pf) - pl;                                              \
            Bc = fmaf(a, Bc, pl);                                                   \
            A *= a;                                                                 \
            HSTEP(xb[s])                                                            \
        }
        S1(0)  S1(1)  S1(2)  S1(3)  S1(4)  S1(5)  S1(6)  S1(7)
        S1(8)  S1(9)  S1(10) S1(11) S1(12) S1(13) S1(14) S1(15)
#undef S1
    }

    if (c < NC - 1)
        *(float4*)&hstart[((size_t)(c + 1) * BB + b) * 4] = make_float4(h0, h1, h2, h3);
    ((float2*)AB)[(size_t)c * BB + b] = make_float2(A, Bc);
}

// ---------------- middle pass: exact chunk-start latents ----------------
__global__ __launch_bounds__(256) void bkt_mid(
    const float* __restrict__ AB, const float* __restrict__ prior,
    float* __restrict__ latstart)
{
    const int b = blockIdx.x * 256 + threadIdx.x;   // 8192 threads
    float L = prior[0];
#pragma unroll
    for (int c = 0; c < NC; ++c) {
        latstart[(size_t)c * BB + b] = L;
        const float2 ab = ((const float2*)AB)[(size_t)c * BB + b];
        L = fmaf(ab.x, L, ab.y);
    }
}

// ---------------- sweep 2: full outputs + loss ----------------
__global__ __launch_bounds__(256, 4) void bkt_sweep2(
    const float* __restrict__ x, const float* __restrict__ y,
    const float* __restrict__ Wxh, const float* __restrict__ Whh,
    const float* __restrict__ bh, const float* __restrict__ Wy,
    const float* __restrict__ by,
    const float* __restrict__ hstart, const float* __restrict__ latstart,
    float* __restrict__ corrects, float* __restrict__ latents,
    float* __restrict__ partials)
{
    const int tid = blockIdx.x * 256 + threadIdx.x;
    const int b = tid & (BB - 1);
    const int c = tid >> 13;
    const float NL2E = -1.44269504088896340736f;

    LOAD_WHH();
    const float wy00=sgpr(Wy[0]*NL2E),  wy01=sgpr(Wy[1]*NL2E),
                wy02=sgpr(Wy[2]*NL2E),  wy03=sgpr(Wy[3]*NL2E),
                wy10=sgpr(Wy[4]*NL2E),  wy11=sgpr(Wy[5]*NL2E),
                wy12=sgpr(Wy[6]*NL2E),  wy13=sgpr(Wy[7]*NL2E),
                wy20=sgpr(Wy[8]*NL2E),  wy21=sgpr(Wy[9]*NL2E),
                wy22=sgpr(Wy[10]*NL2E), wy23=sgpr(Wy[11]*NL2E),
                wy30=sgpr(Wy[12]*NL2E), wy31=sgpr(Wy[13]*NL2E),
                wy32=sgpr(Wy[14]*NL2E), wy33=sgpr(Wy[15]*NL2E);
    const float by0=sgpr(by[0]*NL2E), by1=sgpr(by[1]*NL2E),
                by2=sgpr(by[2]*NL2E), by3=sgpr(by[3]*NL2E);

    const float* xr = x + (size_t)b * TT;
    const float* yr = y + (size_t)b * TT;
    float* cr = corrects + (size_t)b * TT;
    float* lr = latents  + (size_t)b * TT;

    float lat = latstart[(size_t)c * BB + b];
    float h0, h1, h2, h3;
    if (c) {
        float4 hv = *(const float4*)&hstart[((size_t)c * BB + b) * 4];
        h0 = hv.x; h1 = hv.y; h2 = hv.z; h3 = hv.w;
    } else {
        h0 = h1 = h2 = h3 = 0.f;
    }

    float lacc = 0.f;
    float xb[16], yb[16], cb[16], lb[16];
    int t0 = c * CL;

    for (int blk = 0; blk < CL / 16; ++blk, t0 += 16) {
        ld16(xb, xr + t0);
        ld16(yb, yr + t0);
#define S2(s)                                                                       \
        {                                                                           \
            float zl = fmaf(h3,wy30,fmaf(h2,wy20,fmaf(h1,wy10,fmaf(h0,wy00,by0)))); \
            float zf = fmaf(h3,wy31,fmaf(h2,wy21,fmaf(h1,wy11,fmaf(h0,wy01,by1)))); \
            float zg = fmaf(h3,wy32,fmaf(h2,wy22,fmaf(h1,wy12,fmaf(h0,wy02,by2)))); \
            float zs = fmaf(h3,wy33,fmaf(h2,wy23,fmaf(h1,wy13,fmaf(h0,wy03,by3)))); \
            float pl = sig2(zl), pf = sig2(zf), pg = sig2(zg), ps = sig2(zs);       \
            float correct = fmaf(lat, (1.f - ps) - pg, pg);                         \
            float nl      = fmaf(lat, (1.f - pf) - pl, pl);                         \
            float cc  = fminf(fmaxf(correct, 1e-7f), 1.f - 1e-7f);                  \
            float arg = fmaf(yb[s], fmaf(2.f, cc, -1.f), 1.f - cc);                 \
            lacc += __builtin_amdgcn_logf(arg);                                     \
            cb[s] = correct; lb[s] = nl; lat = nl;                                  \
            HSTEP(xb[s])                                                            \
        }
        S2(0)  S2(1)  S2(2)  S2(3)  S2(4)  S2(5)  S2(6)  S2(7)
        S2(8)  S2(9)  S2(10) S2(11) S2(12) S2(13) S2(14) S2(15)
#undef S2
        st16(cr + t0, cb);
        st16(lr + t0, lb);
    }

#pragma unroll
    for (int off = 32; off; off >>= 1) lacc += __shfl_down(lacc, off);
    if ((threadIdx.x & 63) == 0) partials[tid >> 6] = lacc;
}

__global__ __launch_bounds__(64) void bkt_loss(const float* __restrict__ partials, int n,
                                               float* __restrict__ out_loss)
{
    double s = 0.0;
    for (int i = threadIdx.x; i < n; i += 64) s += (double)partials[i];
#pragma unroll
    for (int off = 32; off; off >>= 1) s += __shfl_down(s, off);
    if (threadIdx.x == 0)
        *out_loss = (float)(-s * 0.69314718055994530942 / ((double)BB * (double)TT));
}

extern "C" void kernel_launch(void* const* d_in, const int* in_sizes, int n_in,
                              void* d_out, int out_size, void* d_ws, size_t ws_size,
                              hipStream_t stream)
{
    const float* x     = (const float*)d_in[0];
    const float* y     = (const float*)d_in[1];
    const float* Wxh   = (const float*)d_in[2];
    const float* Whh   = (const float*)d_in[3];
    const float* bh    = (const float*)d_in[4];
    const float* Wy    = (const float*)d_in[5];
    const float* by    = (const float*)d_in[6];
    const float* prior = (const float*)d_in[7];

    float* out      = (float*)d_out;
    float* corrects = out;
    float* latents  = out + (size_t)BB * TT;
    float* lossp    = out + (size_t)2 * BB * TT;

    // workspace layout (floats)
    float* ws       = (float*)d_ws;
    float* AB       = ws;                                   // NC*BB*2
    float* hstart   = AB + (size_t)NC * BB * 2;             // NC*BB*4
    float* latstart = hstart + (size_t)NC * BB * 4;         // NC*BB
    float* partials = latstart + (size_t)NC * BB;           // NC*BB/64

    const int thr = BB * NC;                                // 262144 (1 lane / chain)

    bkt_sweep1<<<thr / 256, 256, 0, stream>>>(x, Wxh, Whh, bh, Wy, by, AB, hstart);
    bkt_mid<<<BB / 256, 256, 0, stream>>>(AB, prior, latstart);
    bkt_sweep2<<<thr / 256, 256, 0, stream>>>(x, y, Wxh, Whh, bh, Wy, by,
                                              hstart, latstart,
                                              corrects, latents, partials);
    bkt_loss<<<1, 64, 0, stream>>>(partials, thr / 64, lossp);
}

// Round 5
// 177.390 us; speedup vs baseline: 1.3502x; 1.3502x over previous
//
#include <hip/hip_runtime.h>

#define BB 8192
#define TT 2048
// sweep1: chunks of 32 steps, 24-step h warmup
#define NC1 64
#define CL1 32
#define WU  24
// sweep2: chunks of 16 steps
#define NC2 128
#define CL2 16

__device__ __forceinline__ float sig2(float z) {
    return __builtin_amdgcn_rcpf(1.f + __builtin_amdgcn_exp2f(z));
}
__device__ __forceinline__ float sgpr(float v) {
    return __builtin_bit_cast(float, __builtin_amdgcn_readfirstlane(__builtin_bit_cast(int, v)));
}
__device__ __forceinline__ void ld16(float* d, const float* p) {
    *(float4*)(d)      = *(const float4*)(p);
    *(float4*)(d + 4)  = *(const float4*)(p + 4);
    *(float4*)(d + 8)  = *(const float4*)(p + 8);
    *(float4*)(d + 12) = *(const float4*)(p + 12);
}
__device__ __forceinline__ void st16(float* p, const float* d) {
    *(float4*)(p)      = *(const float4*)(d);
    *(float4*)(p + 4)  = *(const float4*)(d + 4);
    *(float4*)(p + 8)  = *(const float4*)(d + 8);
    *(float4*)(p + 12) = *(const float4*)(d + 12);
}

#define LOAD_WHH()                                                                  \
    const float wh00=sgpr(Whh[0]*NL2E),  wh01=sgpr(Whh[1]*NL2E),                    \
                wh02=sgpr(Whh[2]*NL2E),  wh03=sgpr(Whh[3]*NL2E),                    \
                wh10=sgpr(Whh[4]*NL2E),  wh11=sgpr(Whh[5]*NL2E),                    \
                wh12=sgpr(Whh[6]*NL2E),  wh13=sgpr(Whh[7]*NL2E),                    \
                wh20=sgpr(Whh[8]*NL2E),  wh21=sgpr(Whh[9]*NL2E),                    \
                wh22=sgpr(Whh[10]*NL2E), wh23=sgpr(Whh[11]*NL2E),                   \
                wh30=sgpr(Whh[12]*NL2E), wh31=sgpr(Whh[13]*NL2E),                   \
                wh32=sgpr(Whh[14]*NL2E), wh33=sgpr(Whh[15]*NL2E);                   \
    const float wx0=sgpr(Wxh[0]*NL2E), wx1=sgpr(Wxh[1]*NL2E),                       \
                wx2=sgpr(Wxh[2]*NL2E), wx3=sgpr(Wxh[3]*NL2E);                       \
    const float bh0=sgpr(bh[0]*NL2E), bh1=sgpr(bh[1]*NL2E),                         \
                bh2=sgpr(bh[2]*NL2E), bh3=sgpr(bh[3]*NL2E);

#define HSTEP(xs)                                                                   \
    {                                                                               \
        float z0 = fmaf(h3,wh30,fmaf(h2,wh20,fmaf(h1,wh10,fmaf(h0,wh00,fmaf(xs,wx0,bh0))))); \
        float z1 = fmaf(h3,wh31,fmaf(h2,wh21,fmaf(h1,wh11,fmaf(h0,wh01,fmaf(xs,wx1,bh1))))); \
        float z2 = fmaf(h3,wh32,fmaf(h2,wh22,fmaf(h1,wh12,fmaf(h0,wh02,fmaf(xs,wx2,bh2))))); \
        float z3 = fmaf(h3,wh33,fmaf(h2,wh23,fmaf(h1,wh13,fmaf(h0,wh03,fmaf(xs,wx3,bh3))))); \
        h0 = sig2(z0); h1 = sig2(z1); h2 = sig2(z2); h3 = sig2(z3);                 \
    }

// ---- sweep 1: lane = (row b, 32-step chunk c1); emits h snapshots + (A,B) per 16 ----
__global__ __launch_bounds__(256, 6) void bkt_sweep1(
    const float* __restrict__ x, const float* __restrict__ Wxh,
    const float* __restrict__ Whh, const float* __restrict__ bh,
    const float* __restrict__ Wy, const float* __restrict__ by,
    float* __restrict__ Aarr, float* __restrict__ Barr,
    float4* __restrict__ hstart4)
{
    const int tid = blockIdx.x * 256 + threadIdx.x;   // = b*64 + c1
    const int c1 = tid & (NC1 - 1);
    const int b  = tid >> 6;
    const float NL2E = -1.44269504088896340736f;

    LOAD_WHH();
    const float wl0=sgpr(Wy[0]*NL2E),  wl1=sgpr(Wy[4]*NL2E),
                wl2=sgpr(Wy[8]*NL2E),  wl3=sgpr(Wy[12]*NL2E);
    const float wf0=sgpr(Wy[1]*NL2E),  wf1=sgpr(Wy[5]*NL2E),
                wf2=sgpr(Wy[9]*NL2E),  wf3=sgpr(Wy[13]*NL2E);
    const float byl=sgpr(by[0]*NL2E), byf=sgpr(by[1]*NL2E);

    const float* xr = x + (size_t)b * TT;
    const int t0 = c1 * CL1;
    float h0=0.f, h1=0.f, h2=0.f, h3=0.f;
    float xb[32];

    // ---- warmup: 24 steps from clamped start (lane c1==0 result discarded) ----
    {
        const float* wp = xr + (t0 >= WU ? t0 - WU : 0);
        ld16(xb, wp);
        *(float4*)(xb + 16) = *(const float4*)(wp + 16);
        *(float4*)(xb + 20) = *(const float4*)(wp + 20);
        HSTEP(xb[0])  HSTEP(xb[1])  HSTEP(xb[2])  HSTEP(xb[3])
        HSTEP(xb[4])  HSTEP(xb[5])  HSTEP(xb[6])  HSTEP(xb[7])
        HSTEP(xb[8])  HSTEP(xb[9])  HSTEP(xb[10]) HSTEP(xb[11])
        HSTEP(xb[12]) HSTEP(xb[13]) HSTEP(xb[14]) HSTEP(xb[15])
        HSTEP(xb[16]) HSTEP(xb[17]) HSTEP(xb[18]) HSTEP(xb[19])
        HSTEP(xb[20]) HSTEP(xb[21]) HSTEP(xb[22]) HSTEP(xb[23])
        if (c1 == 0) { h0 = h1 = h2 = h3 = 0.f; }   // exact start
    }

    // snapshot: h entering chunk c2 = 2*c1
    hstart4[(size_t)b * NC2 + 2 * c1] = make_float4(h0, h1, h2, h3);

    // ---- main 32 steps: full chunk in registers (wave burst = contiguous 8 KB) ----
    ld16(xb, xr + t0);
    ld16(xb + 16, xr + t0 + 16);

    float Aacc = 1.f, Bacc = 0.f;
#define S1(s)                                                                       \
    {                                                                               \
        float zl = fmaf(h3,wl3,fmaf(h2,wl2,fmaf(h1,wl1,fmaf(h0,wl0,byl))));         \
        float zf = fmaf(h3,wf3,fmaf(h2,wf2,fmaf(h1,wf1,fmaf(h0,wf0,byf))));         \
        float pl = sig2(zl), pf = sig2(zf);                                         \
        float a = (1.f - pf) - pl;                                                  \
        Bacc = fmaf(a, Bacc, pl);                                                   \
        Aacc *= a;                                                                  \
        HSTEP(xb[s])                                                                \
    }
    S1(0)  S1(1)  S1(2)  S1(3)  S1(4)  S1(5)  S1(6)  S1(7)
    S1(8)  S1(9)  S1(10) S1(11) S1(12) S1(13) S1(14) S1(15)

    // snapshot: h entering chunk c2 = 2*c1 + 1; save first window's (A,B)
    hstart4[(size_t)b * NC2 + 2 * c1 + 1] = make_float4(h0, h1, h2, h3);
    const float A0 = Aacc, B0 = Bacc;
    Aacc = 1.f; Bacc = 0.f;

    S1(16) S1(17) S1(18) S1(19) S1(20) S1(21) S1(22) S1(23)
    S1(24) S1(25) S1(26) S1(27) S1(28) S1(29) S1(30) S1(31)
#undef S1

    *(float2*)&Aarr[(size_t)b * NC2 + 2 * c1] = make_float2(A0, Aacc);
    *(float2*)&Barr[(size_t)b * NC2 + 2 * c1] = make_float2(B0, Bacc);
}

// ---- middle pass: exact chunk-start latents (per-row serial over 128 chunks) ----
__global__ __launch_bounds__(256) void bkt_mid(
    const float* __restrict__ Aarr, const float* __restrict__ Barr,
    const float* __restrict__ prior, float* __restrict__ latstart)
{
    const int b = blockIdx.x * 256 + threadIdx.x;   // 8192 threads
    float L = prior[0];
#pragma unroll
    for (int c = 0; c < NC2; ++c) {
        latstart[(size_t)b * NC2 + c] = L;
        L = fmaf(Aarr[(size_t)b * NC2 + c], L, Barr[(size_t)b * NC2 + c]);
    }
}

// ---- sweep 2: lane = (row b, 16-step chunk c2); outputs + loss ----
__global__ __launch_bounds__(256, 4) void bkt_sweep2(
    const float* __restrict__ x, const float* __restrict__ y,
    const float* __restrict__ Wxh, const float* __restrict__ Whh,
    const float* __restrict__ bh, const float* __restrict__ Wy,
    const float* __restrict__ by,
    const float4* __restrict__ hstart4, const float* __restrict__ latstart,
    float* __restrict__ corrects, float* __restrict__ latents,
    float* __restrict__ partials)
{
    const int tid = blockIdx.x * 256 + threadIdx.x;   // = b*128 + c2
    const int c2 = tid & (NC2 - 1);
    const int b  = tid >> 7;
    const float NL2E = -1.44269504088896340736f;

    LOAD_WHH();
    const float wy00=sgpr(Wy[0]*NL2E),  wy01=sgpr(Wy[1]*NL2E),
                wy02=sgpr(Wy[2]*NL2E),  wy03=sgpr(Wy[3]*NL2E),
                wy10=sgpr(Wy[4]*NL2E),  wy11=sgpr(Wy[5]*NL2E),
                wy12=sgpr(Wy[6]*NL2E),  wy13=sgpr(Wy[7]*NL2E),
                wy20=sgpr(Wy[8]*NL2E),  wy21=sgpr(Wy[9]*NL2E),
                wy22=sgpr(Wy[10]*NL2E), wy23=sgpr(Wy[11]*NL2E),
                wy30=sgpr(Wy[12]*NL2E), wy31=sgpr(Wy[13]*NL2E),
                wy32=sgpr(Wy[14]*NL2E), wy33=sgpr(Wy[15]*NL2E);
    const float by0=sgpr(by[0]*NL2E), by1=sgpr(by[1]*NL2E),
                by2=sgpr(by[2]*NL2E), by3=sgpr(by[3]*NL2E);

    const int t0 = c2 * CL2;
    const float* xr = x + (size_t)b * TT + t0;
    const float* yr = y + (size_t)b * TT + t0;

    float xb[16], yb[16], cb[16], lb[16];
    ld16(xb, xr);
    ld16(yb, yr);

    const float4 hv = hstart4[(size_t)b * NC2 + c2];
    float h0 = hv.x, h1 = hv.y, h2 = hv.z, h3 = hv.w;
    float lat = latstart[(size_t)b * NC2 + c2];
    float lacc = 0.f;

#define S2(s)                                                                       \
    {                                                                               \
        float zl = fmaf(h3,wy30,fmaf(h2,wy20,fmaf(h1,wy10,fmaf(h0,wy00,by0))));     \
        float zf = fmaf(h3,wy31,fmaf(h2,wy21,fmaf(h1,wy11,fmaf(h0,wy01,by1))));     \
        float zg = fmaf(h3,wy32,fmaf(h2,wy22,fmaf(h1,wy12,fmaf(h0,wy02,by2))));     \
        float zs = fmaf(h3,wy33,fmaf(h2,wy23,fmaf(h1,wy13,fmaf(h0,wy03,by3))));     \
        float pl = sig2(zl), pf = sig2(zf), pg = sig2(zg), ps = sig2(zs);           \
        float correct = fmaf(lat, (1.f - ps) - pg, pg);                             \
        float nl      = fmaf(lat, (1.f - pf) - pl, pl);                             \
        float cc  = fminf(fmaxf(correct, 1e-7f), 1.f - 1e-7f);                      \
        float arg = fmaf(yb[s], fmaf(2.f, cc, -1.f), 1.f - cc);                     \
        lacc += __builtin_amdgcn_logf(arg);                                         \
        cb[s] = correct; lb[s] = nl; lat = nl;                                      \
        HSTEP(xb[s])                                                                \
    }
    S2(0)  S2(1)  S2(2)  S2(3)  S2(4)  S2(5)  S2(6)  S2(7)
    S2(8)  S2(9)  S2(10) S2(11) S2(12) S2(13) S2(14) S2(15)
#undef S2

    st16(corrects + (size_t)b * TT + t0, cb);
    st16(latents  + (size_t)b * TT + t0, lb);

#pragma unroll
    for (int off = 32; off; off >>= 1) lacc += __shfl_down(lacc, off);
    if ((threadIdx.x & 63) == 0) partials[tid >> 6] = lacc;
}

__global__ __launch_bounds__(256) void bkt_loss(const float* __restrict__ partials, int n,
                                                float* __restrict__ out_loss)
{
    __shared__ double sd[4];
    double s = 0.0;
    for (int i = threadIdx.x; i < n; i += 256) s += (double)partials[i];
#pragma unroll
    for (int off = 32; off; off >>= 1) s += __shfl_down(s, off);
    if ((threadIdx.x & 63) == 0) sd[threadIdx.x >> 6] = s;
    __syncthreads();
    if (threadIdx.x == 0) {
        double t = sd[0] + sd[1] + sd[2] + sd[3];
        *out_loss = (float)(-t * 0.69314718055994530942 / ((double)BB * (double)TT));
    }
}

extern "C" void kernel_launch(void* const* d_in, const int* in_sizes, int n_in,
                              void* d_out, int out_size, void* d_ws, size_t ws_size,
                              hipStream_t stream)
{
    const float* x     = (const float*)d_in[0];
    const float* y     = (const float*)d_in[1];
    const float* Wxh   = (const float*)d_in[2];
    const float* Whh   = (const float*)d_in[3];
    const float* bh    = (const float*)d_in[4];
    const float* Wy    = (const float*)d_in[5];
    const float* by    = (const float*)d_in[6];
    const float* prior = (const float*)d_in[7];

    float* out      = (float*)d_out;
    float* corrects = out;
    float* latents  = out + (size_t)BB * TT;
    float* lossp    = out + (size_t)2 * BB * TT;

    // workspace layout (floats): hstart4 first for 16B alignment
    float*  ws       = (float*)d_ws;
    float4* hstart4  = (float4*)ws;                          // BB*NC2 float4 (16 MB)
    float*  Aarr     = ws + (size_t)BB * NC2 * 4;            // BB*NC2 (4 MB)
    float*  Barr     = Aarr + (size_t)BB * NC2;              // BB*NC2 (4 MB)
    float*  latstart = Barr + (size_t)BB * NC2;              // BB*NC2 (4 MB)
    float*  partials = latstart + (size_t)BB * NC2;          // BB*NC2/64

    const int thr1 = BB * NC1;                               // 524288
    const int thr2 = BB * NC2;                               // 1048576

    bkt_sweep1<<<thr1 / 256, 256, 0, stream>>>(x, Wxh, Whh, bh, Wy, by,
                                               Aarr, Barr, hstart4);
    bkt_mid<<<BB / 256, 256, 0, stream>>>(Aarr, Barr, prior, latstart);
    bkt_sweep2<<<thr2 / 256, 256, 0, stream>>>(x, y, Wxh, Whh, bh, Wy, by,
                                               hstart4, latstart,
                                               corrects, latents, partials);
    bkt_loss<<<1, 256, 0, stream>>>(partials, thr2 / 64, lossp);
}